// Round 8
// baseline (109.755 us; speedup 1.0000x reference)
//
#include <hip/hip_runtime.h>
#include <hip/hip_bf16.h>
#include <stdint.h>

typedef __bf16 bf16;
typedef bf16 bf16x8 __attribute__((ext_vector_type(8)));
typedef bf16 bf16x4 __attribute__((ext_vector_type(4)));
typedef float f32x4 __attribute__((ext_vector_type(4)));

#define MFMA_16x16x32(a, b, c) __builtin_amdgcn_mfma_f32_16x16x32_bf16((a), (b), (c), 0, 0, 0)

// ---- problem sizes ----
constexpr int B = 16, S = 512, H = 768, NH = 12, DH = 64;
constexpr long NHID = (long)B * S * H;          // 6291456
constexpr long NW = (long)8 * H * H;            // 4718592 per weight tensor

// ---- workspace layout (bytes) ----
constexpr size_t XB_OFF = 0;
constexpr size_t XB_SZ  = (size_t)NHID * 2;
constexpr size_t W_SZ   = (size_t)NW * 2;
constexpr size_t WQ_OFF = XB_OFF + XB_SZ;
constexpr size_t WK_OFF = WQ_OFF + W_SZ;
constexpr size_t WV_OFF = WK_OFF + W_SZ;
constexpr size_t PROJ_SZ = (size_t)B * NH * S * DH * 2;  // 12582912
constexpr size_t QB_OFF = WV_OFF + W_SZ;
constexpr size_t KB_OFF = QB_OFF + PROJ_SZ;
constexpr size_t VB_OFF = KB_OFF + PROJ_SZ;              // V^T: [B,NH,DH,S]
constexpr size_t WS_NEED = VB_OFF + PROJ_SZ;

// ---------------- fused f32 -> bf16 convert (hidden + 3 weights) ----------------
__global__ void cvt_all(const float* __restrict__ x,
                        const float* __restrict__ wq, const float* __restrict__ wk,
                        const float* __restrict__ wv,
                        bf16* __restrict__ xb, bf16* __restrict__ wqb,
                        bf16* __restrict__ wkb, bf16* __restrict__ wvb) {
  long i = ((long)blockIdx.x * blockDim.x + threadIdx.x) * 8;
  const float* src;
  bf16* dst;
  long off;
  if (i < NHID)               { src = x;  dst = xb;  off = i; }
  else if (i < NHID + NW)     { src = wq; dst = wqb; off = i - NHID; }
  else if (i < NHID + 2 * NW) { src = wk; dst = wkb; off = i - NHID - NW; }
  else if (i < NHID + 3 * NW) { src = wv; dst = wvb; off = i - NHID - 2 * NW; }
  else return;
  const float4* sp = reinterpret_cast<const float4*>(src + off);
  float4 a = sp[0], b = sp[1];
  bf16x8 o;
  o[0] = (bf16)a.x; o[1] = (bf16)a.y; o[2] = (bf16)a.z; o[3] = (bf16)a.w;
  o[4] = (bf16)b.x; o[5] = (bf16)b.y; o[6] = (bf16)b.z; o[7] = (bf16)b.w;
  *reinterpret_cast<bf16x8*>(dst + off) = o;
}

// ---------------- projection GEMM: 8-wave deep pipeline, counted vmcnt ----------------
// BM=128, BN=192, BK=64. 768 blocks = 16 b x 4 m x 12 n = exactly 3/CU.
// 3 LDS K-tile buffers (120KB): compute buf[t], stage(t+2) in flight across the
// single per-tile barrier: s_waitcnt vmcnt(5) -- NEVER drains to 0 in the loop.
// Each K-tile = 2 planes of [rows][32k] using the round-7 verified 0-conflict
// swizzle (src chunk g=(l&3)^((l>>3)&3), read chunk lg^((r>>1)&3)).
// Q,K written [B,NH,S,DH]; V written TRANSPOSED [B,NH,DH,S].
__global__ __launch_bounds__(512, 2) void proj_gemm(
    const bf16* __restrict__ Xb,
    const bf16* __restrict__ Wqb, const bf16* __restrict__ Wkb, const bf16* __restrict__ Wvb,
    const float* __restrict__ bq, const float* __restrict__ bk, const float* __restrict__ bv,
    const int* __restrict__ eidx,
    bf16* __restrict__ Qb, bf16* __restrict__ Kb, bf16* __restrict__ Vb)
{
  __shared__ __align__(16) bf16 As[3][2 * 128 * 32];   // [buf][kh*4096 + row*32 + k]
  __shared__ __align__(16) bf16 Bs[3][2 * 192 * 32];   // [buf][kh*6144 + row*32 + k]

  // XCD-grouped decode: xcd = blk&7 owns batches {2*xcd, 2*xcd+1}
  const int xcd = blockIdx.x & 7;
  const int bi  = blockIdx.x >> 3;            // 0..95
  const int b   = xcd * 2 + (bi / 48);        // batch
  const int rem = bi % 48;                    // 4 m-tiles x 12 n-tiles
  const int mt  = rem / 12;
  const int nt  = rem % 12;
  const int m0  = mt * 128;
  const int proj = nt >> 2;                   // 192*4 = 768 per projection
  const int n0  = (nt & 3) * 192;             // col offset within projection
  const int e = eidx[b];

  const bf16* W = (proj == 0 ? Wqb : (proj == 1 ? Wkb : Wvb)) + (size_t)e * H * H;
  const float* bias = (proj == 0 ? bq : (proj == 1 ? bk : bv)) + (size_t)e * H;
  bf16* Out = (proj == 0 ? Qb : (proj == 1 ? Kb : Vb));

  const int tid = threadIdx.x;
  const int lane = tid & 63;
  const int wave = tid >> 6;                  // 0..7
  const int wm = wave >> 2, wn = wave & 3;    // 2 x 64 m, 4 x 48 n
  const int r = lane & 15, lg = lane >> 4;

  const bf16* Abase = Xb + ((size_t)b * S + m0) * H;
  const bf16* Bbase = W + (size_t)n0 * H;

  const int srow = lane >> 2;                          // 0..15 within 16-row unit
  const int sg = ((lane & 3) ^ ((lane >> 3) & 3)) * 8; // pre-swizzled source chunk

  // stage one K-tile (BK=64 = 2 planes of 32): 5 gload_lds calls per thread.
  // A: 16 units (2 planes x 8), B: 24 units (2 planes x 12); unit = 16 rows x 32 k.
  auto stage = [&](int kt, int pb) {
    const int k0 = kt * 64;
#pragma unroll
    for (int i = 0; i < 2; ++i) {
      const int u = wave * 2 + i;                      // 0..15
      const int kh = u >> 3, p = u & 7;
      const bf16* ga = Abase + (size_t)(p * 16 + srow) * H + k0 + kh * 32 + sg;
      __builtin_amdgcn_global_load_lds(
          (const __attribute__((address_space(1))) void*)ga,
          (__attribute__((address_space(3))) void*)(&As[pb][u * 512]), 16, 0, 0);
    }
#pragma unroll
    for (int i = 0; i < 3; ++i) {
      const int u = wave * 3 + i;                      // 0..23
      const int kh = u / 12, p = u % 12;
      const bf16* gb = Bbase + (size_t)(p * 16 + srow) * H + k0 + kh * 32 + sg;
      __builtin_amdgcn_global_load_lds(
          (const __attribute__((address_space(1))) void*)gb,
          (__attribute__((address_space(3))) void*)(&Bs[pb][u * 512]), 16, 0, 0);
    }
  };

  f32x4 acc[4][3] = {};

  stage(0, 0);
  stage(1, 1);
  // tile 0 ready; tile 1's 5 loads stay in flight
  asm volatile("s_waitcnt vmcnt(5) lgkmcnt(0)\n\ts_barrier" ::: "memory");

  const int sz = (r >> 1) & 3;   // read-side swizzle index

  int buf = 0, nb = 2;           // nb = (t+2)%3
#pragma unroll 1
  for (int t = 0; t < 12; ++t) {
    if (t + 2 < 12) stage(t + 2, nb);

    const bf16* Ab = &As[buf][0];
    const bf16* Bb = &Bs[buf][0];
#pragma unroll
    for (int kh = 0; kh < 2; ++kh) {
      bf16x8 bfr[3];
#pragma unroll
      for (int ni = 0; ni < 3; ++ni)
        bfr[ni] = *reinterpret_cast<const bf16x8*>(
            &Bb[kh * 6144 + (wn * 48 + ni * 16 + r) * 32 + ((lg ^ sz) * 8)]);
#pragma unroll
      for (int half = 0; half < 2; ++half) {
        bf16x8 af0 = *reinterpret_cast<const bf16x8*>(
            &Ab[kh * 4096 + (wm * 64 + (half * 2) * 16 + r) * 32 + ((lg ^ sz) * 8)]);
        bf16x8 af1 = *reinterpret_cast<const bf16x8*>(
            &Ab[kh * 4096 + (wm * 64 + (half * 2 + 1) * 16 + r) * 32 + ((lg ^ sz) * 8)]);
        __builtin_amdgcn_s_setprio(1);
#pragma unroll
        for (int ni = 0; ni < 3; ++ni) {
          acc[half * 2][ni]     = MFMA_16x16x32(af0, bfr[ni], acc[half * 2][ni]);
          acc[half * 2 + 1][ni] = MFMA_16x16x32(af1, bfr[ni], acc[half * 2 + 1][ni]);
        }
        __builtin_amdgcn_s_setprio(0);
      }
    }

    // boundary: tile t+1 must be resident; tile t+2's 5 loads stay in flight
    if (t < 10)
      asm volatile("s_waitcnt vmcnt(5) lgkmcnt(0)\n\ts_barrier" ::: "memory");
    else if (t == 10)
      asm volatile("s_waitcnt vmcnt(0) lgkmcnt(0)\n\ts_barrier" ::: "memory");
    buf = (buf == 2) ? 0 : buf + 1;
    nb  = (nb == 2) ? 0 : nb + 1;
  }

  // epilogue: bias add, cast bf16
  if (proj != 2) {
    // Q,K: [B,NH,S,DH] scatter
#pragma unroll
    for (int ni = 0; ni < 3; ++ni) {
      const int col = n0 + wn * 48 + ni * 16 + r;
      const int nh = col >> 6, dh = col & 63;
      const float bb = bias[col];
      bf16* orow = Out + ((size_t)b * NH + nh) * S * DH + dh;
#pragma unroll
      for (int mi = 0; mi < 4; ++mi) {
#pragma unroll
        for (int rr = 0; rr < 4; ++rr) {
          const int srow2 = m0 + wm * 64 + mi * 16 + lg * 4 + rr;
          orow[(size_t)srow2 * DH] = (bf16)(acc[mi][ni][rr] + bb);
        }
      }
    }
  } else {
    // V^T: [B,NH,DH,S]; 4 consecutive rows -> vector store
#pragma unroll
    for (int ni = 0; ni < 3; ++ni) {
      const int col = n0 + wn * 48 + ni * 16 + r;
      const int nh = col >> 6, dh = col & 63;
      const float bb = bias[col];
      bf16* orow = Out + ((size_t)b * NH + nh) * DH * S + (size_t)dh * S;
#pragma unroll
      for (int mi = 0; mi < 4; ++mi) {
        bf16x4 v;
#pragma unroll
        for (int rr = 0; rr < 4; ++rr) v[rr] = (bf16)(acc[mi][ni][rr] + bb);
        *reinterpret_cast<bf16x4*>(orow + m0 + wm * 64 + mi * 16 + lg * 4) = v;
      }
    }
  }
}

// ---------------- fused attention: LDS double-buffered K/V^T pipeline ----------------
// 1536 blocks (192 heads x 8 q-blocks of 64 rows), 256 threads = 4 waves.
__global__ __launch_bounds__(256, 4) void attn_kernel(
    const bf16* __restrict__ Qb, const bf16* __restrict__ Kb, const bf16* __restrict__ VTb,
    const float* __restrict__ mask, float* __restrict__ out)
{
  __shared__ __align__(16) bf16 Ks[2][64 * 64];
  __shared__ __align__(16) bf16 Vs[2][64 * 64];
  __shared__ float maskS[512];

  const int x = blockIdx.x;
  const int xcd = x & 7;
  const int grp = x >> 3;
  const int qblk = grp & 7;
  const int bh = (grp >> 3) * 8 + xcd;       // bijective over 1536 = 8*8*24
  const int b = bh / NH;
  const int h = bh % NH;
  const int tid = threadIdx.x;
  const int wave = tid >> 6;
  const int lane = tid & 63;
  const int r = lane & 15, lg = lane >> 4;
  const int q0 = qblk * 64 + wave * 16;

  const bf16* Q  = Qb  + (size_t)bh * S * DH;
  const bf16* K  = Kb  + (size_t)bh * S * DH;
  const bf16* VT = VTb + (size_t)bh * DH * S;   // [DH][S]

  for (int i = tid; i < S; i += 256) maskS[i] = mask[b * S + i];

  const int srowoff = lane >> 3;                 // 0..7
  const int sg = (lane & 7) ^ srowoff;           // pre-swizzled source chunk

  auto stage = [&](int kt, int buf) {
    const int kb = kt * 64;
#pragma unroll
    for (int i = 0; i < 2; ++i) {
      const int c = wave * 2 + i;                // 0..7
      const int row = c * 8 + srowoff;
      const bf16* gk = K + (size_t)(kb + row) * DH + sg * 8;
      __builtin_amdgcn_global_load_lds(
          (const __attribute__((address_space(1))) void*)gk,
          (__attribute__((address_space(3))) void*)(&Ks[buf][c * 512]), 16, 0, 0);
      const bf16* gv = VT + (size_t)row * S + kb + sg * 8;
      __builtin_amdgcn_global_load_lds(
          (const __attribute__((address_space(1))) void*)gv,
          (__attribute__((address_space(3))) void*)(&Vs[buf][c * 512]), 16, 0, 0);
    }
  };

  // hoisted Q fragments (this wave's 16 q-rows)
  const bf16x8 qf0 = *reinterpret_cast<const bf16x8*>(&Q[(size_t)(q0 + r) * DH + lg * 8]);
  const bf16x8 qf1 = *reinterpret_cast<const bf16x8*>(&Q[(size_t)(q0 + r) * DH + 32 + lg * 8]);

  stage(0, 0);
  __syncthreads();   // drains vmcnt(0)+lgkmcnt(0)

  float m = -3.0e38f, l = 0.0f;
  f32x4 ctx[4] = {};
  int buf = 0;

#pragma unroll 1
  for (int kt = 0; kt < 8; ++kt) {
    const int kb = kt * 64;
    if (kt < 7) stage(kt + 1, buf ^ 1);   // prefetch flies under this tile's compute

    // QK^T (swapped) from LDS: 4 k-subtiles of 16, K=64 in two MFMA steps
    f32x4 sa[4];
#pragma unroll
    for (int t = 0; t < 4; ++t) {
      const int row = t * 16 + r;
      const int sw = row & 7;
      bf16x8 kf0 = *reinterpret_cast<const bf16x8*>(&Ks[buf][row * 64 + ((lg ^ sw) * 8)]);
      bf16x8 kf1 = *reinterpret_cast<const bf16x8*>(&Ks[buf][row * 64 + (((lg + 4) ^ sw) * 8)]);
      f32x4 a = {};
      a = MFMA_16x16x32(kf0, qf0, a);
      a = MFMA_16x16x32(kf1, qf1, a);
      sa[t] = a;
    }

    // online softmax (lane's q = q0+r; k = kb + t*16 + lg*4 + rr)
    float tmax = -3.0e38f;
#pragma unroll
    for (int t = 0; t < 4; ++t)
#pragma unroll
      for (int rr = 0; rr < 4; ++rr) {
        float s = sa[t][rr] * 0.125f + maskS[kb + t * 16 + lg * 4 + rr];
        sa[t][rr] = s;
        tmax = fmaxf(tmax, s);
      }
    tmax = fmaxf(tmax, __shfl_xor(tmax, 16));
    tmax = fmaxf(tmax, __shfl_xor(tmax, 32));
    const float mnew = fmaxf(m, tmax);
    const float scale = __expf(m - mnew);
    m = mnew;
    float ps = 0.f;
#pragma unroll
    for (int t = 0; t < 4; ++t)
#pragma unroll
      for (int rr = 0; rr < 4; ++rr) {
        float p = __expf(sa[t][rr] - mnew);
        sa[t][rr] = p;
        ps += p;
      }
    l = l * scale + ps;
#pragma unroll
    for (int dt = 0; dt < 4; ++dt) ctx[dt] *= scale;

    // PV from LDS V^T tile: ctx^T[d][q] += V^T[d][k] * P^T[k][q]
#pragma unroll
    for (int kc = 0; kc < 2; ++kc) {
      bf16x8 pf;
      f32x4 p0 = sa[2 * kc], p1 = sa[2 * kc + 1];
      pf[0] = (bf16)p0[0]; pf[1] = (bf16)p0[1]; pf[2] = (bf16)p0[2]; pf[3] = (bf16)p0[3];
      pf[4] = (bf16)p1[0]; pf[5] = (bf16)p1[1]; pf[6] = (bf16)p1[2]; pf[7] = (bf16)p1[3];
      const int chunk_lo = kc * 4 + (lg >> 1);
      const int rem = (lg & 1) * 4;              // elements
#pragma unroll
      for (int dt = 0; dt < 4; ++dt) {
        const int row = dt * 16 + r;
        const int sw = row & 7;
        const bf16* vlo = &Vs[buf][row * 64 + ((chunk_lo ^ sw) * 8) + rem];
        const bf16* vhi = &Vs[buf][row * 64 + (((chunk_lo + 2) ^ sw) * 8) + rem];
        bf16x4 lo = *reinterpret_cast<const bf16x4*>(vlo);
        bf16x4 hi = *reinterpret_cast<const bf16x4*>(vhi);
        bf16x8 vf;
        vf[0] = lo[0]; vf[1] = lo[1]; vf[2] = lo[2]; vf[3] = lo[3];
        vf[4] = hi[0]; vf[5] = hi[1]; vf[6] = hi[2]; vf[7] = hi[3];
        ctx[dt] = MFMA_16x16x32(vf, pf, ctx[dt]);
      }
    }

    __syncthreads();   // drains vmcnt (next tile staged) + all waves done with buf
    buf ^= 1;
  }

  l += __shfl_xor(l, 16);
  l += __shfl_xor(l, 32);
  const float inv = 1.0f / l;

  // write ctx (f32, vectorized): lane's q = q0+r, d = dt*16 + lg*4 + rr
  float* obase = out + ((size_t)b * S + q0 + r) * H + h * DH;
#pragma unroll
  for (int dt = 0; dt < 4; ++dt) {
    float4 o;
    o.x = ctx[dt][0] * inv; o.y = ctx[dt][1] * inv;
    o.z = ctx[dt][2] * inv; o.w = ctx[dt][3] * inv;
    *reinterpret_cast<float4*>(obase + dt * 16 + lg * 4) = o;
  }
}

extern "C" void kernel_launch(void* const* d_in, const int* in_sizes, int n_in,
                              void* d_out, int out_size, void* d_ws, size_t ws_size,
                              hipStream_t stream) {
  const float* hidden = (const float*)d_in[0];
  const float* mask   = (const float*)d_in[1];
  const float* Wq = (const float*)d_in[2];
  const float* bq = (const float*)d_in[3];
  const float* Wk = (const float*)d_in[4];
  const float* bk = (const float*)d_in[5];
  const float* Wv = (const float*)d_in[6];
  const float* bv = (const float*)d_in[7];
  const int* eidx = (const int*)d_in[8];

  if (ws_size < WS_NEED) return;

  char* ws = (char*)d_ws;
  bf16* Xb  = (bf16*)(ws + XB_OFF);
  bf16* Wqb = (bf16*)(ws + WQ_OFF);
  bf16* Wkb = (bf16*)(ws + WK_OFF);
  bf16* Wvb = (bf16*)(ws + WV_OFF);
  bf16* Qbf = (bf16*)(ws + QB_OFF);
  bf16* Kbf = (bf16*)(ws + KB_OFF);
  bf16* Vbf = (bf16*)(ws + VB_OFF);
  float* out = (float*)d_out;

  // (NHID + 3*NW) / 8 / 256 = 9984 blocks exactly
  cvt_all<<<9984, 256, 0, stream>>>(hidden, Wq, Wk, Wv, Xb, Wqb, Wkb, Wvb);
  proj_gemm<<<768, 512, 0, stream>>>(Xb, Wqb, Wkb, Wvb, bq, bk, bv, eidx,
                                     Qbf, Kbf, Vbf);
  attn_kernel<<<1536, 256, 0, stream>>>(Qbf, Kbf, Vbf, mask, out);
}

// Round 9
// 100.411 us; speedup vs baseline: 1.0931x; 1.0931x over previous
//
#include <hip/hip_runtime.h>
#include <hip/hip_bf16.h>
#include <stdint.h>

typedef __bf16 bf16;
typedef bf16 bf16x8 __attribute__((ext_vector_type(8)));
typedef bf16 bf16x4 __attribute__((ext_vector_type(4)));
typedef float f32x4 __attribute__((ext_vector_type(4)));

#define MFMA_16x16x32(a, b, c) __builtin_amdgcn_mfma_f32_16x16x32_bf16((a), (b), (c), 0, 0, 0)

// ---- problem sizes ----
constexpr int B = 16, S = 512, H = 768, NH = 12, DH = 64;

// ---- workspace layout (bytes): only Q/K/V bf16 now ----
constexpr size_t PROJ_SZ = (size_t)B * NH * S * DH * 2;  // 12582912
constexpr size_t QB_OFF = 0;
constexpr size_t KB_OFF = QB_OFF + PROJ_SZ;
constexpr size_t VB_OFF = KB_OFF + PROJ_SZ;              // V^T: [B,NH,DH,S]
constexpr size_t WS_NEED = VB_OFF + PROJ_SZ;

// ---------------- projection GEMM: fused f32->bf16 reg-staging ----------------
// 576 blocks = 8 XCD-groups x (2 batches x 2 m-tiles x 18 n-tiles), 512 thr.
// BM=256, BN=128, BK=32, dbuf. Reads X and W[e] as f32 DIRECTLY (no cvt pass):
// each thread: 6x float4 global loads (issued one tile ahead, T14 split),
// in-register f32->bf16, 3x ds_write_b128 into the swizzled layout.
// Swizzle (verified 0-conflict read path, R7): LDS[row][c ^ ((row>>1)&3)] holds
// global chunk c; reads use chunk lg ^ ((r>>1)&3).
// Q,K written [B,NH,S,DH]; V written TRANSPOSED [B,NH,DH,S].
__global__ __launch_bounds__(512, 2) void proj_gemm(
    const float* __restrict__ Xf,
    const float* __restrict__ Wqf, const float* __restrict__ Wkf, const float* __restrict__ Wvf,
    const float* __restrict__ bq, const float* __restrict__ bk, const float* __restrict__ bv,
    const int* __restrict__ eidx,
    bf16* __restrict__ Qb, bf16* __restrict__ Kb, bf16* __restrict__ Vb)
{
  __shared__ __align__(16) bf16 As[2][256 * 32];   // 32 KB
  __shared__ __align__(16) bf16 Bs[2][128 * 32];   // 16 KB

  // XCD-grouped decode: xcd = blk&7 owns batches {2*xcd, 2*xcd+1}
  const int xcd = blockIdx.x & 7;
  const int bi  = blockIdx.x >> 3;            // 0..71
  const int b   = xcd * 2 + (bi / 36);        // batch
  const int rem = bi % 36;                    // 2 m-tiles x 18 n-tiles
  const int m0  = (rem / 18) * 256;
  const int gy  = rem % 18;
  const int proj = gy / 6;
  const int n0 = (gy % 6) * 128;
  const int e = eidx[b];

  const float* W = (proj == 0 ? Wqf : (proj == 1 ? Wkf : Wvf)) + (size_t)e * H * H;
  const float* bias = (proj == 0 ? bq : (proj == 1 ? bk : bv)) + (size_t)e * H;
  bf16* Out = (proj == 0 ? Qb : (proj == 1 ? Kb : Vb));

  const int tid = threadIdx.x;
  const int lane = tid & 63;
  const int wave = tid >> 6;                  // 0..7
  const int wm = wave >> 1, wn = wave & 1;    // 4 x 64 m, 2 x 64 n
  const int r = lane & 15, lg = lane >> 4;

  // ---- staging assignment (f32 sources) ----
  const int rowA = tid >> 1, ha = tid & 1;    // 2 thr/row, 16 k-elems each
  const int rowB = tid >> 2, qB = tid & 3;    // 4 thr/row, 8 k-elems each
  const float* gA = Xf + ((size_t)b * S + m0 + rowA) * H + ha * 16;
  const float* gB = W + (size_t)(n0 + rowB) * H + qB * 8;
  const int sA = (rowA >> 1) & 3, sB = (rowB >> 1) & 3;
  const int slotA0 = ((ha * 2)     ^ sA) * 8;
  const int slotA1 = ((ha * 2 + 1) ^ sA) * 8;
  const int slotB  = (qB ^ sB) * 8;

  f32x4 la0, la1, la2, la3, lb0, lb1;
  auto loads = [&](int kt) {
    const float* a = gA + kt * 32;
    la0 = *reinterpret_cast<const f32x4*>(a);
    la1 = *reinterpret_cast<const f32x4*>(a + 4);
    la2 = *reinterpret_cast<const f32x4*>(a + 8);
    la3 = *reinterpret_cast<const f32x4*>(a + 12);
    const float* bb = gB + kt * 32;
    lb0 = *reinterpret_cast<const f32x4*>(bb);
    lb1 = *reinterpret_cast<const f32x4*>(bb + 4);
  };
  auto pack = [](f32x4 x, f32x4 y) {
    bf16x8 o;
    o[0] = (bf16)x[0]; o[1] = (bf16)x[1]; o[2] = (bf16)x[2]; o[3] = (bf16)x[3];
    o[4] = (bf16)y[0]; o[5] = (bf16)y[1]; o[6] = (bf16)y[2]; o[7] = (bf16)y[3];
    return o;
  };
  auto writeT = [&](int pb) {
    *reinterpret_cast<bf16x8*>(&As[pb][rowA * 32 + slotA0]) = pack(la0, la1);
    *reinterpret_cast<bf16x8*>(&As[pb][rowA * 32 + slotA1]) = pack(la2, la3);
    *reinterpret_cast<bf16x8*>(&Bs[pb][rowB * 32 + slotB])  = pack(lb0, lb1);
  };

  f32x4 acc[4][4] = {};

  loads(0);
  writeT(0);          // compiler inserts vmcnt wait before first use
  loads(1);           // tile 1 in flight during tile-0 compute
  asm volatile("s_waitcnt lgkmcnt(0)\n\ts_barrier" ::: "memory");

  const int sz = (r >> 1) & 3;   // read-side swizzle index

  int buf = 0;
#pragma unroll 1
  for (int kt = 0; kt < 24; ++kt) {
    bf16x8 af[4], bfr[4];
#pragma unroll
    for (int mi = 0; mi < 4; ++mi)
      af[mi] = *reinterpret_cast<const bf16x8*>(
          &As[buf][(wm * 64 + mi * 16 + r) * 32 + ((lg ^ sz) * 8)]);
#pragma unroll
    for (int ni = 0; ni < 4; ++ni)
      bfr[ni] = *reinterpret_cast<const bf16x8*>(
          &Bs[buf][(wn * 64 + ni * 16 + r) * 32 + ((lg ^ sz) * 8)]);
    __builtin_amdgcn_s_setprio(1);
#pragma unroll
    for (int mi = 0; mi < 4; ++mi)
#pragma unroll
      for (int ni = 0; ni < 4; ++ni)
        acc[mi][ni] = MFMA_16x16x32(af[mi], bfr[ni], acc[mi][ni]);
    __builtin_amdgcn_s_setprio(0);

    if (kt < 23) {
      writeT(buf ^ 1);            // consume in-flight loads (tile kt+1)
      if (kt < 22) loads(kt + 2); // refill; flies across barrier + next compute
      asm volatile("s_waitcnt lgkmcnt(0)\n\ts_barrier" ::: "memory");
    }
    buf ^= 1;
  }

  // epilogue: bias add, cast bf16
  if (proj != 2) {
    // Q,K: [B,NH,S,DH] scatter
#pragma unroll
    for (int ni = 0; ni < 4; ++ni) {
      const int col = n0 + wn * 64 + ni * 16 + r;
      const int nh = col >> 6, dh = col & 63;
      const float bb = bias[col];
      bf16* orow = Out + ((size_t)b * NH + nh) * S * DH + dh;
#pragma unroll
      for (int mi = 0; mi < 4; ++mi) {
#pragma unroll
        for (int rr = 0; rr < 4; ++rr) {
          const int srow2 = m0 + wm * 64 + mi * 16 + lg * 4 + rr;
          orow[(size_t)srow2 * DH] = (bf16)(acc[mi][ni][rr] + bb);
        }
      }
    }
  } else {
    // V^T: [B,NH,DH,S]; 4 consecutive rows -> vector store
#pragma unroll
    for (int ni = 0; ni < 4; ++ni) {
      const int col = n0 + wn * 64 + ni * 16 + r;
      const int nh = col >> 6, dh = col & 63;
      const float bb = bias[col];
      bf16* orow = Out + ((size_t)b * NH + nh) * DH * S + (size_t)dh * S;
#pragma unroll
      for (int mi = 0; mi < 4; ++mi) {
        bf16x4 v;
#pragma unroll
        for (int rr = 0; rr < 4; ++rr) v[rr] = (bf16)(acc[mi][ni][rr] + bb);
        *reinterpret_cast<bf16x4*>(orow + m0 + wm * 64 + mi * 16 + lg * 4) = v;
      }
    }
  }
}

// ---------------- fused attention: LDS double-buffered K/V^T pipeline ----------------
// 1536 blocks (192 heads x 8 q-blocks of 64 rows), 256 threads = 4 waves.
__global__ __launch_bounds__(256, 4) void attn_kernel(
    const bf16* __restrict__ Qb, const bf16* __restrict__ Kb, const bf16* __restrict__ VTb,
    const float* __restrict__ mask, float* __restrict__ out)
{
  __shared__ __align__(16) bf16 Ks[2][64 * 64];
  __shared__ __align__(16) bf16 Vs[2][64 * 64];
  __shared__ float maskS[512];

  const int x = blockIdx.x;
  const int xcd = x & 7;
  const int grp = x >> 3;
  const int qblk = grp & 7;
  const int bh = (grp >> 3) * 8 + xcd;       // bijective over 1536 = 8*8*24
  const int b = bh / NH;
  const int h = bh % NH;
  const int tid = threadIdx.x;
  const int wave = tid >> 6;
  const int lane = tid & 63;
  const int r = lane & 15, lg = lane >> 4;
  const int q0 = qblk * 64 + wave * 16;

  const bf16* Q  = Qb  + (size_t)bh * S * DH;
  const bf16* K  = Kb  + (size_t)bh * S * DH;
  const bf16* VT = VTb + (size_t)bh * DH * S;   // [DH][S]

  for (int i = tid; i < S; i += 256) maskS[i] = mask[b * S + i];

  const int srowoff = lane >> 3;                 // 0..7
  const int sg = (lane & 7) ^ srowoff;           // pre-swizzled source chunk

  auto stage = [&](int kt, int buf) {
    const int kb = kt * 64;
#pragma unroll
    for (int i = 0; i < 2; ++i) {
      const int c = wave * 2 + i;                // 0..7
      const int row = c * 8 + srowoff;
      const bf16* gk = K + (size_t)(kb + row) * DH + sg * 8;
      __builtin_amdgcn_global_load_lds(
          (const __attribute__((address_space(1))) void*)gk,
          (__attribute__((address_space(3))) void*)(&Ks[buf][c * 512]), 16, 0, 0);
      const bf16* gv = VT + (size_t)row * S + kb + sg * 8;
      __builtin_amdgcn_global_load_lds(
          (const __attribute__((address_space(1))) void*)gv,
          (__attribute__((address_space(3))) void*)(&Vs[buf][c * 512]), 16, 0, 0);
    }
  };

  // hoisted Q fragments (this wave's 16 q-rows)
  const bf16x8 qf0 = *reinterpret_cast<const bf16x8*>(&Q[(size_t)(q0 + r) * DH + lg * 8]);
  const bf16x8 qf1 = *reinterpret_cast<const bf16x8*>(&Q[(size_t)(q0 + r) * DH + 32 + lg * 8]);

  stage(0, 0);
  __syncthreads();   // drains vmcnt(0)+lgkmcnt(0)

  float m = -3.0e38f, l = 0.0f;
  f32x4 ctx[4] = {};
  int buf = 0;

#pragma unroll 1
  for (int kt = 0; kt < 8; ++kt) {
    const int kb = kt * 64;
    if (kt < 7) stage(kt + 1, buf ^ 1);   // prefetch flies under this tile's compute

    // QK^T (swapped) from LDS: 4 k-subtiles of 16, K=64 in two MFMA steps
    f32x4 sa[4];
#pragma unroll
    for (int t = 0; t < 4; ++t) {
      const int row = t * 16 + r;
      const int sw = row & 7;
      bf16x8 kf0 = *reinterpret_cast<const bf16x8*>(&Ks[buf][row * 64 + ((lg ^ sw) * 8)]);
      bf16x8 kf1 = *reinterpret_cast<const bf16x8*>(&Ks[buf][row * 64 + (((lg + 4) ^ sw) * 8)]);
      f32x4 a = {};
      a = MFMA_16x16x32(kf0, qf0, a);
      a = MFMA_16x16x32(kf1, qf1, a);
      sa[t] = a;
    }

    // online softmax (lane's q = q0+r; k = kb + t*16 + lg*4 + rr)
    float tmax = -3.0e38f;
#pragma unroll
    for (int t = 0; t < 4; ++t)
#pragma unroll
      for (int rr = 0; rr < 4; ++rr) {
        float s = sa[t][rr] * 0.125f + maskS[kb + t * 16 + lg * 4 + rr];
        sa[t][rr] = s;
        tmax = fmaxf(tmax, s);
      }
    tmax = fmaxf(tmax, __shfl_xor(tmax, 16));
    tmax = fmaxf(tmax, __shfl_xor(tmax, 32));
    const float mnew = fmaxf(m, tmax);
    const float scale = __expf(m - mnew);
    m = mnew;
    float ps = 0.f;
#pragma unroll
    for (int t = 0; t < 4; ++t)
#pragma unroll
      for (int rr = 0; rr < 4; ++rr) {
        float p = __expf(sa[t][rr] - mnew);
        sa[t][rr] = p;
        ps += p;
      }
    l = l * scale + ps;
#pragma unroll
    for (int dt = 0; dt < 4; ++dt) ctx[dt] *= scale;

    // PV from LDS V^T tile: ctx^T[d][q] += V^T[d][k] * P^T[k][q]
#pragma unroll
    for (int kc = 0; kc < 2; ++kc) {
      bf16x8 pf;
      f32x4 p0 = sa[2 * kc], p1 = sa[2 * kc + 1];
      pf[0] = (bf16)p0[0]; pf[1] = (bf16)p0[1]; pf[2] = (bf16)p0[2]; pf[3] = (bf16)p0[3];
      pf[4] = (bf16)p1[0]; pf[5] = (bf16)p1[1]; pf[6] = (bf16)p1[2]; pf[7] = (bf16)p1[3];
      const int chunk_lo = kc * 4 + (lg >> 1);
      const int rem = (lg & 1) * 4;              // elements
#pragma unroll
      for (int dt = 0; dt < 4; ++dt) {
        const int row = dt * 16 + r;
        const int sw = row & 7;
        const bf16* vlo = &Vs[buf][row * 64 + ((chunk_lo ^ sw) * 8) + rem];
        const bf16* vhi = &Vs[buf][row * 64 + (((chunk_lo + 2) ^ sw) * 8) + rem];
        bf16x4 lo = *reinterpret_cast<const bf16x4*>(vlo);
        bf16x4 hi = *reinterpret_cast<const bf16x4*>(vhi);
        bf16x8 vf;
        vf[0] = lo[0]; vf[1] = lo[1]; vf[2] = lo[2]; vf[3] = lo[3];
        vf[4] = hi[0]; vf[5] = hi[1]; vf[6] = hi[2]; vf[7] = hi[3];
        ctx[dt] = MFMA_16x16x32(vf, pf, ctx[dt]);
      }
    }

    __syncthreads();   // drains vmcnt (next tile staged) + all waves done with buf
    buf ^= 1;
  }

  l += __shfl_xor(l, 16);
  l += __shfl_xor(l, 32);
  const float inv = 1.0f / l;

  // write ctx (f32, vectorized): lane's q = q0+r, d = dt*16 + lg*4 + rr
  float* obase = out + ((size_t)b * S + q0 + r) * H + h * DH;
#pragma unroll
  for (int dt = 0; dt < 4; ++dt) {
    float4 o;
    o.x = ctx[dt][0] * inv; o.y = ctx[dt][1] * inv;
    o.z = ctx[dt][2] * inv; o.w = ctx[dt][3] * inv;
    *reinterpret_cast<float4*>(obase + dt * 16 + lg * 4) = o;
  }
}

extern "C" void kernel_launch(void* const* d_in, const int* in_sizes, int n_in,
                              void* d_out, int out_size, void* d_ws, size_t ws_size,
                              hipStream_t stream) {
  const float* hidden = (const float*)d_in[0];
  const float* mask   = (const float*)d_in[1];
  const float* Wq = (const float*)d_in[2];
  const float* bq = (const float*)d_in[3];
  const float* Wk = (const float*)d_in[4];
  const float* bk = (const float*)d_in[5];
  const float* Wv = (const float*)d_in[6];
  const float* bv = (const float*)d_in[7];
  const int* eidx = (const int*)d_in[8];

  if (ws_size < WS_NEED) return;

  char* ws = (char*)d_ws;
  bf16* Qbf = (bf16*)(ws + QB_OFF);
  bf16* Kbf = (bf16*)(ws + KB_OFF);
  bf16* Vbf = (bf16*)(ws + VB_OFF);
  float* out = (float*)d_out;

  proj_gemm<<<576, 512, 0, stream>>>(hidden, Wq, Wk, Wv, bq, bk, bv, eidx,
                                     Qbf, Kbf, Vbf);
  attn_kernel<<<1536, 256, 0, stream>>>(Qbf, Kbf, Vbf, mask, out);
}